// Round 1
// 964.278 us; speedup vs baseline: 1.1268x; 1.1268x over previous
//
#include <hip/hip_runtime.h>
#include <math.h>

#define VOCAB 50257
#define EMB 16
#define BS 8
#define MCW 512
#define NTOK (BS*MCW)   // 4096
#define TT 32           // token tile in logits kernel
#define VCH 1024        // vocab chunk per block in logits kernel

// ---------------- K1: embedding lookup + Q/K/V projections ----------------
__global__ __launch_bounds__(256) void qkv_kernel(
    const int* __restrict__ x, const float* __restrict__ emb,
    const float* __restrict__ Wq, const float* __restrict__ bq,
    const float* __restrict__ Wk, const float* __restrict__ bk,
    const float* __restrict__ Wv, const float* __restrict__ bv,
    float* __restrict__ Q, float* __restrict__ K, float* __restrict__ V)
{
    int t = blockIdx.x * 256 + threadIdx.x;
    if (t >= NTOK) return;
    int id = x[t];
    float e[EMB];
    #pragma unroll
    for (int j = 0; j < EMB; j++) e[j] = emb[(size_t)id*EMB + j];
    #pragma unroll
    for (int o = 0; o < EMB; o++) {
        float aq = bq[o], ak = bk[o], av = bv[o];
        #pragma unroll
        for (int j = 0; j < EMB; j++) {
            aq += e[j]*Wq[o*EMB+j];
            ak += e[j]*Wk[o*EMB+j];
            av += e[j]*Wv[o*EMB+j];
        }
        Q[t*EMB+o] = aq; K[t*EMB+o] = ak; V[t*EMB+o] = av;
    }
}

// ---------------- K2: masked scores + axis-1 (query-dim) softmax ----------
// One 64-thread block per (b, k) column. Softmax is over q for fixed (b,k).
// Writes weights transposed: WT[b][k][q]  (coalesced over q).
__global__ __launch_bounds__(64) void attn_softmax_kernel(
    const float* __restrict__ Q, const float* __restrict__ K,
    float* __restrict__ WT)
{
    int b = blockIdx.x >> 9;     // /512
    int k = blockIdx.x & 511;
    int lane = threadIdx.x;      // 0..63

    float kr[EMB];
    const float* kp = K + (size_t)(b*MCW + k)*EMB;
    #pragma unroll
    for (int j = 0; j < EMB; j++) kr[j] = kp[j];

    float s[8];
    #pragma unroll
    for (int i = 0; i < 8; i++) {
        int q = lane + 64*i;
        const float* qp = Q + (size_t)(b*MCW + q)*EMB;
        float acc = 0.f;
        #pragma unroll
        for (int j = 0; j < EMB; j++) acc += qp[j]*kr[j];
        // mask: valid iff k <= q; masked -> 0 -> -inf. Also exact-zero -> -inf.
        if (q < k || acc == 0.0f) acc = -INFINITY;
        s[i] = acc;
    }
    // max over the 512 q values: local, then wave butterfly
    float m = s[0];
    #pragma unroll
    for (int i = 1; i < 8; i++) m = fmaxf(m, s[i]);
    #pragma unroll
    for (int off = 32; off; off >>= 1) m = fmaxf(m, __shfl_xor(m, off));

    float w[8];
    float sum = 0.f;
    #pragma unroll
    for (int i = 0; i < 8; i++) { w[i] = expf(s[i] - m); sum += w[i]; }
    #pragma unroll
    for (int off = 32; off; off >>= 1) sum += __shfl_xor(sum, off);

    float inv = 1.0f / sum;
    float* wp = WT + (size_t)(b*MCW + k)*MCW;
    #pragma unroll
    for (int i = 0; i < 8; i++) wp[lane + 64*i] = w[i]*inv;
}

// ---------------- K3: out[b,w,e] = sum_p WT[b][p][w] * V[b][p][e] ---------
__global__ __launch_bounds__(1024) void apply_kernel(
    const float* __restrict__ WT, const float* __restrict__ V,
    float* __restrict__ O)
{
    int b  = blockIdx.x >> 3;
    int w0 = (blockIdx.x & 7) * 64;
    int w  = w0 + (threadIdx.x & 63);
    int e  = threadIdx.x >> 6;     // 0..15
    const float* wt = WT + (size_t)b*MCW*MCW + w;   // stride MCW over p
    const float* vp = V  + (size_t)b*MCW*EMB + e;   // stride EMB over p
    float acc = 0.f;
    #pragma unroll 8
    for (int p = 0; p < MCW; p++)
        acc += wt[(size_t)p*MCW] * vp[(size_t)p*EMB];
    O[(size_t)(b*MCW + w)*EMB + e] = acc;
}

// ---------------- K4: logits = O @ Wl^T + bl  (the 823 MB store) ----------
// Grid: (ceil(VOCAB/VCH)=50, NTOK/TT=128). Block: 256 threads.
// Thread owns 4 vocab rows: v = vc*VCH + tid + {0,256,512,768}  (Wl rows in
// registers); out-rows for TT tokens broadcast from LDS; dword stores are
// lane-consecutive (coalesced).
// ROUND-0 CHANGE: plain stores (no nontemporal). Theory: nt no-allocate on
// misaligned dword streams (VOCAB odd -> every row a different 64B phase)
// defeats L2 write-combining -> partial-line HBM RMW -> ~0.9 TB/s effective.
// Plain stores let L2 merge; the fill kernel proves 6.3 TB/s is reachable.
__global__ __launch_bounds__(256) void logits_kernel(
    const float* __restrict__ O, const float* __restrict__ Wl,
    const float* __restrict__ bl, float* __restrict__ out)
{
    __shared__ float orow[TT*EMB];   // 512 floats
    int vc  = blockIdx.x;
    int t0  = blockIdx.y * TT;
    int tid = threadIdx.x;

    orow[tid]       = O[(size_t)t0*EMB + tid];
    orow[tid + 256] = O[(size_t)t0*EMB + tid + 256];
    __syncthreads();

    int vbase = vc*VCH + tid;
    bool full = ((vc+1)*VCH <= VOCAB);   // chunks 0..48: all 4 rows valid
    float wl[4][EMB];
    float blv[4];
    bool  ok[4];
    #pragma unroll
    for (int r = 0; r < 4; r++) {
        int v = vbase + 256*r;
        ok[r] = (v < VOCAB);
        int vv = ok[r] ? v : 0;
        const float* wp = Wl + (size_t)vv*EMB;
        #pragma unroll
        for (int j = 0; j < EMB; j++) wl[r][j] = wp[j];
        blv[r] = bl[vv];
    }

    size_t base = (size_t)t0*VOCAB + (size_t)vbase;
    for (int t = 0; t < TT; t++) {
        float o[EMB];
        #pragma unroll
        for (int j = 0; j < EMB; j++) o[j] = orow[t*EMB + j];
        float r0 = blv[0], r1 = blv[1], r2 = blv[2], r3 = blv[3];
        #pragma unroll
        for (int j = 0; j < EMB; j++) {
            r0 += o[j]*wl[0][j];
            r1 += o[j]*wl[1][j];
            r2 += o[j]*wl[2][j];
            r3 += o[j]*wl[3][j];
        }
        if (full) {
            out[base]       = r0;
            out[base + 256] = r1;
            out[base + 512] = r2;
            out[base + 768] = r3;
        } else {
            if (ok[0]) out[base]       = r0;
            if (ok[1]) out[base + 256] = r1;
            if (ok[2]) out[base + 512] = r2;
            if (ok[3]) out[base + 768] = r3;
        }
        base += VOCAB;
    }
}

extern "C" void kernel_launch(void* const* d_in, const int* in_sizes, int n_in,
                              void* d_out, int out_size, void* d_ws, size_t ws_size,
                              hipStream_t stream) {
    const int*   x   = (const int*)  d_in[0];
    const float* emb = (const float*)d_in[1];
    const float* Wq  = (const float*)d_in[2];
    const float* bq  = (const float*)d_in[3];
    const float* Wk  = (const float*)d_in[4];
    const float* bk  = (const float*)d_in[5];
    const float* Wv  = (const float*)d_in[6];
    const float* bv  = (const float*)d_in[7];
    const float* Wl  = (const float*)d_in[8];
    const float* bl  = (const float*)d_in[9];
    float* out = (float*)d_out;
    float* ws  = (float*)d_ws;

    // Workspace: Q,K,V,O = 4 * 4096*16 floats = 1 MB total.
    float* Q = ws;
    float* K = ws + (size_t)NTOK*EMB;
    float* V = ws + (size_t)2*NTOK*EMB;
    float* O = ws + (size_t)3*NTOK*EMB;
    // Attention weights (8 MB) staged inside d_out (823 MB); K4 overwrites
    // every element of d_out afterwards, and the stream serializes K2->K3->K4.
    float* WT = out;

    qkv_kernel<<<(NTOK + 255)/256, 256, 0, stream>>>(x, emb, Wq, bq, Wk, bk, Wv, bv, Q, K, V);
    attn_softmax_kernel<<<BS*MCW, 64, 0, stream>>>(Q, K, WT);
    apply_kernel<<<BS*8, 1024, 0, stream>>>(WT, V, O);
    dim3 g4((VOCAB + VCH - 1)/VCH, NTOK/TT);
    logits_kernel<<<g4, 256, 0, stream>>>(O, Wl, bl, out);
}